// Round 1
// baseline (882.204 us; speedup 1.0000x reference)
//
#include <hip/hip_runtime.h>
#include <math.h>

// GATLinkPredictor on MI355X.
// Pipeline: gemm1(+alpha epilogue) -> CSR build (count/offsets/scatter)
//           -> gat1 (per-node wave softmax+aggregate, fused bias+ELU)
//           -> gemm2(+alpha epilogue) -> gat2 -> decode (dot+sigmoid).

constexpr float NEG_SLOPE = 0.2f;

__device__ __forceinline__ float lrelu(float x) { return x > 0.f ? x : NEG_SLOPE * x; }

// ---------------- GEMM1: h1 = x @ W1, plus per-head alpha_s/alpha_d ----------------
// x:[N,128], W1:[128,64], h1:[N,64]; asn/adn:[N,8]
__global__ __launch_bounds__(256) void gemm1_kernel(
    const float* __restrict__ X, const float* __restrict__ W,
    const float* __restrict__ a_s, const float* __restrict__ a_d,
    float* __restrict__ H, float* __restrict__ asn, float* __restrict__ adn, int N)
{
    __shared__ float Wl[128 * 64];
    __shared__ float Xl[4][128];
    int tid = threadIdx.x;
    // stage W (32 KB) with float4
    const float4* W4 = (const float4*)W;
    float4* Wl4 = (float4*)Wl;
    for (int i = tid; i < 128 * 64 / 4; i += 256) Wl4[i] = W4[i];
    int w = tid >> 6, lane = tid & 63;
    int row = blockIdx.x * 4 + w;
    if (row < N) {
        const float* xr = X + (size_t)row * 128;
        Xl[w][lane] = xr[lane];
        Xl[w][lane + 64] = xr[lane + 64];
    }
    __syncthreads();
    if (row >= N) return;
    float acc = 0.f;
#pragma unroll 8
    for (int k = 0; k < 128; ++k) acc += Xl[w][k] * Wl[k * 64 + lane];
    H[(size_t)row * 64 + lane] = acc;
    // alpha epilogue: col = h*8+c, a_s/a_d are [8][8] row-major -> index == lane
    float ps = acc * a_s[lane];
    float pd = acc * a_d[lane];
#pragma unroll
    for (int d = 1; d < 8; d <<= 1) { ps += __shfl_xor(ps, d); pd += __shfl_xor(pd, d); }
    int h = lane >> 3, c = lane & 7;
    if (c == 0) { asn[row * 8 + h] = ps; adn[row * 8 + h] = pd; }
}

// ---------------- GEMM2: z = h2 @ W2, plus scalar alpha_s/alpha_d ----------------
__global__ __launch_bounds__(256) void gemm2_kernel(
    const float* __restrict__ X, const float* __restrict__ W,
    const float* __restrict__ a_s, const float* __restrict__ a_d,
    float* __restrict__ H, float* __restrict__ asn, float* __restrict__ adn, int N)
{
    __shared__ float Wl[64 * 64];
    __shared__ float Xl[4][64];
    int tid = threadIdx.x;
    const float4* W4 = (const float4*)W;
    float4* Wl4 = (float4*)Wl;
    for (int i = tid; i < 64 * 64 / 4; i += 256) Wl4[i] = W4[i];
    int w = tid >> 6, lane = tid & 63;
    int row = blockIdx.x * 4 + w;
    if (row < N) Xl[w][lane] = X[(size_t)row * 64 + lane];
    __syncthreads();
    if (row >= N) return;
    float acc = 0.f;
#pragma unroll 8
    for (int k = 0; k < 64; ++k) acc += Xl[w][k] * Wl[k * 64 + lane];
    H[(size_t)row * 64 + lane] = acc;
    float ps = acc * a_s[lane];
    float pd = acc * a_d[lane];
#pragma unroll
    for (int d = 1; d < 64; d <<= 1) { ps += __shfl_xor(ps, d); pd += __shfl_xor(pd, d); }
    if (lane == 0) { asn[row] = ps; adn[row] = pd; }
}

// ---------------- CSR build ----------------
__global__ void count_kernel(const int* __restrict__ dst, int E, int* __restrict__ cnt)
{
    for (int e = blockIdx.x * blockDim.x + threadIdx.x; e < E; e += gridDim.x * blockDim.x)
        atomicAdd(&cnt[dst[e]], 1);
}

// per-wave scan of (count[n]+1), single atomic per wave on a cursor; ranges need not be
// ordered by node id. Writes the self-loop into slot 0 and inits fill=1.
__global__ __launch_bounds__(256) void offsets_kernel(
    const int* __restrict__ cnt, int N, int* __restrict__ offv,
    int* __restrict__ fill, int* __restrict__ csr, int* __restrict__ cursor)
{
    int n = blockIdx.x * blockDim.x + threadIdx.x;
    int lane = threadIdx.x & 63;
    int v = (n < N) ? (cnt[n] + 1) : 0;
    int incl = v;
#pragma unroll
    for (int d = 1; d < 64; d <<= 1) {
        int t = __shfl_up(incl, d);
        if (lane >= d) incl += t;
    }
    int total = __shfl(incl, 63);
    int base = 0;
    if (lane == 63) base = atomicAdd(cursor, total);
    base = __shfl(base, 63);
    if (n < N) {
        int o = base + incl - v;
        offv[n] = o;
        csr[o] = n;   // self loop
        fill[n] = 1;
    }
}

__global__ void scatter_kernel(const int* __restrict__ src, const int* __restrict__ dst, int E,
                               const int* __restrict__ offv, int* __restrict__ fill,
                               int* __restrict__ csr)
{
    for (int e = blockIdx.x * blockDim.x + threadIdx.x; e < E; e += gridDim.x * blockDim.x) {
        int d = dst[e];
        int pos = offv[d] + atomicAdd(&fill[d], 1);
        csr[pos] = src[e];
    }
}

// ---------------- GAT layer 1: 8 heads x 8 channels, fused bias + ELU ----------------
__global__ __launch_bounds__(256) void gat1_kernel(
    const float* __restrict__ h1, const float* __restrict__ asn, const float* __restrict__ adn,
    const float* __restrict__ b1, const int* __restrict__ offv, const int* __restrict__ cnt,
    const int* __restrict__ csr, float* __restrict__ h2, int N)
{
    int n = blockIdx.x * 4 + (threadIdx.x >> 6);
    if (n >= N) return;
    int lane = threadIdx.x & 63;
    int base = offv[n];
    int deg = cnt[n] + 1;

    // phase 1: per-head max & exp-sum. lane = j*8 + h (8 edges-parallel x 8 heads)
    int h = lane & 7, j = lane >> 3;
    float ad_h = adn[n * 8 + h];
    float mx = -INFINITY;
    for (int k = j; k < deg; k += 8) {
        int s = csr[base + k];
        mx = fmaxf(mx, lrelu(asn[s * 8 + h] + ad_h));
    }
    mx = fmaxf(mx, __shfl_xor(mx, 8));
    mx = fmaxf(mx, __shfl_xor(mx, 16));
    mx = fmaxf(mx, __shfl_xor(mx, 32));
    float sm = 0.f;
    for (int k = j; k < deg; k += 8) {
        int s = csr[base + k];
        sm += __expf(lrelu(asn[s * 8 + h] + ad_h) - mx);
    }
    sm += __shfl_xor(sm, 8);
    sm += __shfl_xor(sm, 16);
    sm += __shfl_xor(sm, 32);
    float denom = sm + 1e-16f;

    // phase 2: lane = channel (h*8+c). Pull this lane's head stats from lane==head.
    int hh = lane >> 3;
    float mxh = __shfl(mx, hh);
    float dnh = __shfl(denom, hh);
    float adhh = adn[n * 8 + hh];
    float acc = 0.f;
    for (int k = 0; k < deg; ++k) {
        int s = csr[base + k];
        float e = lrelu(asn[s * 8 + hh] + adhh);
        float alpha = __expf(e - mxh) / dnh;
        acc += alpha * h1[(size_t)s * 64 + lane];
    }
    float v = acc + b1[lane];
    h2[(size_t)n * 64 + lane] = v > 0.f ? v : __expf(v) - 1.f;  // ELU
}

// ---------------- GAT layer 2: 1 head x 64 channels, fused bias ----------------
__global__ __launch_bounds__(256) void gat2_kernel(
    const float* __restrict__ z, const float* __restrict__ asn, const float* __restrict__ adn,
    const float* __restrict__ b2, const int* __restrict__ offv, const int* __restrict__ cnt,
    const int* __restrict__ csr, float* __restrict__ out, int N)
{
    int n = blockIdx.x * 4 + (threadIdx.x >> 6);
    if (n >= N) return;
    int lane = threadIdx.x & 63;
    int base = offv[n];
    int deg = cnt[n] + 1;
    float ad_n = adn[n];
    float mx = -INFINITY;
    for (int k = lane; k < deg; k += 64) {
        int s = csr[base + k];
        mx = fmaxf(mx, lrelu(asn[s] + ad_n));
    }
#pragma unroll
    for (int d = 1; d < 64; d <<= 1) mx = fmaxf(mx, __shfl_xor(mx, d));
    float sm = 0.f;
    for (int k = lane; k < deg; k += 64) {
        int s = csr[base + k];
        sm += __expf(lrelu(asn[s] + ad_n) - mx);
    }
#pragma unroll
    for (int d = 1; d < 64; d <<= 1) sm += __shfl_xor(sm, d);
    float denom = sm + 1e-16f;
    float acc = 0.f;
    for (int k = 0; k < deg; ++k) {
        int s = csr[base + k];
        float alpha = __expf(lrelu(asn[s] + ad_n) - mx) / denom;
        acc += alpha * z[(size_t)s * 64 + lane];
    }
    out[(size_t)n * 64 + lane] = acc + b2[lane];
}

// ---------------- decode: sigmoid(dot(z2[q0], z2[q1])) ----------------
__global__ __launch_bounds__(256) void decode_kernel(
    const float* __restrict__ z2, const int* __restrict__ q, int Q, float* __restrict__ out)
{
    int i = blockIdx.x * 4 + (threadIdx.x >> 6);
    if (i >= Q) return;
    int lane = threadIdx.x & 63;
    int a = q[i], b = q[Q + i];
    float v = z2[(size_t)a * 64 + lane] * z2[(size_t)b * 64 + lane];
#pragma unroll
    for (int d = 1; d < 64; d <<= 1) v += __shfl_xor(v, d);
    if (lane == 0) out[i] = 1.f / (1.f + __expf(-v));
}

extern "C" void kernel_launch(void* const* d_in, const int* in_sizes, int n_in,
                              void* d_out, int out_size, void* d_ws, size_t ws_size,
                              hipStream_t stream)
{
    const float* x   = (const float*)d_in[0];
    const int*   ei  = (const int*)d_in[1];
    const int*   qe  = (const int*)d_in[2];
    const float* W1  = (const float*)d_in[3];
    const float* as1 = (const float*)d_in[4];
    const float* ad1 = (const float*)d_in[5];
    const float* b1  = (const float*)d_in[6];
    const float* W2  = (const float*)d_in[7];
    const float* as2 = (const float*)d_in[8];
    const float* ad2 = (const float*)d_in[9];
    const float* b2  = (const float*)d_in[10];

    const int N = in_sizes[0] / 128;
    const int E = in_sizes[1] / 2;
    const int Q = in_sizes[2] / 2;

    float* out = (float*)d_out;

    // workspace layout (256B aligned)
    char* ws = (char*)d_ws;
    size_t o = 0;
    auto alloc = [&](size_t bytes) -> void* {
        void* p = ws + o;
        o += (bytes + 255) & ~(size_t)255;
        return p;
    };
    float* bufA  = (float*)alloc((size_t)N * 64 * 4);  // h1, later z
    float* bufB  = (float*)alloc((size_t)N * 64 * 4);  // h2, later z2
    float* asn1  = (float*)alloc((size_t)N * 8 * 4);
    float* adn1  = (float*)alloc((size_t)N * 8 * 4);
    float* asn2  = (float*)alloc((size_t)N * 4);
    float* adn2  = (float*)alloc((size_t)N * 4);
    int*   cnt   = (int*)alloc((size_t)N * 4);
    int*   offv  = (int*)alloc((size_t)N * 4);
    int*   fill  = (int*)alloc((size_t)N * 4);
    int*   cursor= (int*)alloc(256);
    int*   csr   = (int*)alloc((size_t)(E + N) * 4);

    const int* esrc = ei;
    const int* edst = ei + E;

    hipMemsetAsync(cnt, 0, (size_t)N * 4, stream);
    hipMemsetAsync(cursor, 0, 4, stream);

    int nodeBlocks4 = (N + 3) / 4;        // 4 waves per block, 1 node per wave
    int edgeBlocks  = (E + 255) / 256;
    int nodeBlocks  = (N + 255) / 256;

    // layer 1 projection + alphas
    gemm1_kernel<<<nodeBlocks4, 256, 0, stream>>>(x, W1, as1, ad1, bufA, asn1, adn1, N);
    // CSR
    count_kernel<<<edgeBlocks, 256, 0, stream>>>(edst, E, cnt);
    offsets_kernel<<<nodeBlocks, 256, 0, stream>>>(cnt, N, offv, fill, csr, cursor);
    scatter_kernel<<<edgeBlocks, 256, 0, stream>>>(esrc, edst, E, offv, fill, csr);
    // layer 1 attention + aggregate (+bias+ELU) -> bufB
    gat1_kernel<<<nodeBlocks4, 256, 0, stream>>>(bufA, asn1, adn1, b1, offv, cnt, csr, bufB, N);
    // layer 2 projection + alphas -> bufA (h1 dead)
    gemm2_kernel<<<nodeBlocks4, 256, 0, stream>>>(bufB, W2, as2, ad2, bufA, asn2, adn2, N);
    // layer 2 attention + aggregate (+bias) -> bufB (h2 dead)
    gat2_kernel<<<nodeBlocks4, 256, 0, stream>>>(bufA, asn2, adn2, b2, offv, cnt, csr, bufB, N);
    // decode
    decode_kernel<<<(Q + 3) / 4, 256, 0, stream>>>(bufB, qe, Q, out);
}

// Round 2
// 570.258 us; speedup vs baseline: 1.5470x; 1.5470x over previous
//
#include <hip/hip_runtime.h>
#include <math.h>

constexpr float NEG_SLOPE = 0.2f;

__device__ __forceinline__ float lrelu(float x) { return x > 0.f ? x : NEG_SLOPE * x; }

__device__ __forceinline__ float readlane_f(float v, int l) {
    return __uint_as_float(__builtin_amdgcn_readlane(__float_as_uint(v), l));
}
__device__ __forceinline__ int readlane_i(int v, int l) {
    return __builtin_amdgcn_readlane(v, l);
}

// ---------------- GEMM1: h1 = x @ W1 (+ per-head alpha epilogue), 2 rows/wave ----------------
__global__ __launch_bounds__(256) void gemm1_kernel(
    const float* __restrict__ X, const float* __restrict__ W,
    const float* __restrict__ a_s, const float* __restrict__ a_d,
    float* __restrict__ H, float* __restrict__ asn, float* __restrict__ adn, int N)
{
    __shared__ float Wl[128 * 64];
    int tid = threadIdx.x;
    const float4* W4 = (const float4*)W;
    float4* Wl4 = (float4*)Wl;
    for (int i = tid; i < 128 * 64 / 4; i += 256) Wl4[i] = W4[i];
    int w = tid >> 6, lane = tid & 63;
    int r0 = blockIdx.x * 8 + w * 2;
    int r1 = r0 + 1;
    float x00 = 0.f, x01 = 0.f, x10 = 0.f, x11 = 0.f;
    if (r0 < N) { x00 = X[(size_t)r0 * 128 + lane]; x01 = X[(size_t)r0 * 128 + 64 + lane]; }
    if (r1 < N) { x10 = X[(size_t)r1 * 128 + lane]; x11 = X[(size_t)r1 * 128 + 64 + lane]; }
    __syncthreads();
    if (r0 >= N) return;
    float a0 = 0.f, a1 = 0.f;
#pragma unroll
    for (int k = 0; k < 64; ++k) {
        float wv = Wl[k * 64 + lane];
        a0 += readlane_f(x00, k) * wv;
        a1 += readlane_f(x10, k) * wv;
    }
#pragma unroll
    for (int k = 0; k < 64; ++k) {
        float wv = Wl[(k + 64) * 64 + lane];
        a0 += readlane_f(x01, k) * wv;
        a1 += readlane_f(x11, k) * wv;
    }
    float avs = a_s[lane], avd = a_d[lane];
    int h = lane >> 3, c = lane & 7;
    {
        H[(size_t)r0 * 64 + lane] = a0;
        float ps = a0 * avs, pd = a0 * avd;
#pragma unroll
        for (int d = 1; d < 8; d <<= 1) { ps += __shfl_xor(ps, d); pd += __shfl_xor(pd, d); }
        if (c == 0) { asn[r0 * 8 + h] = ps; adn[r0 * 8 + h] = pd; }
    }
    if (r1 < N) {
        H[(size_t)r1 * 64 + lane] = a1;
        float ps = a1 * avs, pd = a1 * avd;
#pragma unroll
        for (int d = 1; d < 8; d <<= 1) { ps += __shfl_xor(ps, d); pd += __shfl_xor(pd, d); }
        if (c == 0) { asn[r1 * 8 + h] = ps; adn[r1 * 8 + h] = pd; }
    }
}

// ---------------- GEMM2: z = h2 @ W2 (+ scalar alpha epilogue), 2 rows/wave ----------------
__global__ __launch_bounds__(256) void gemm2_kernel(
    const float* __restrict__ X, const float* __restrict__ W,
    const float* __restrict__ a_s, const float* __restrict__ a_d,
    float* __restrict__ H, float* __restrict__ asn, float* __restrict__ adn, int N)
{
    __shared__ float Wl[64 * 64];
    int tid = threadIdx.x;
    const float4* W4 = (const float4*)W;
    float4* Wl4 = (float4*)Wl;
    for (int i = tid; i < 64 * 64 / 4; i += 256) Wl4[i] = W4[i];
    int w = tid >> 6, lane = tid & 63;
    int r0 = blockIdx.x * 8 + w * 2;
    int r1 = r0 + 1;
    float x0 = 0.f, x1 = 0.f;
    if (r0 < N) x0 = X[(size_t)r0 * 64 + lane];
    if (r1 < N) x1 = X[(size_t)r1 * 64 + lane];
    __syncthreads();
    if (r0 >= N) return;
    float a0 = 0.f, a1 = 0.f;
#pragma unroll
    for (int k = 0; k < 64; ++k) {
        float wv = Wl[k * 64 + lane];
        a0 += readlane_f(x0, k) * wv;
        a1 += readlane_f(x1, k) * wv;
    }
    float avs = a_s[lane], avd = a_d[lane];
    {
        H[(size_t)r0 * 64 + lane] = a0;
        float ps = a0 * avs, pd = a0 * avd;
#pragma unroll
        for (int d = 1; d < 64; d <<= 1) { ps += __shfl_xor(ps, d); pd += __shfl_xor(pd, d); }
        if (lane == 0) { asn[r0] = ps; adn[r0] = pd; }
    }
    if (r1 < N) {
        H[(size_t)r1 * 64 + lane] = a1;
        float ps = a1 * avs, pd = a1 * avd;
#pragma unroll
        for (int d = 1; d < 64; d <<= 1) { ps += __shfl_xor(ps, d); pd += __shfl_xor(pd, d); }
        if (lane == 0) { asn[r1] = ps; adn[r1] = pd; }
    }
}

// ---------------- CSR build ----------------
__global__ void count_kernel(const int* __restrict__ dst, int E, int* __restrict__ cnt)
{
    for (int e = blockIdx.x * blockDim.x + threadIdx.x; e < E; e += gridDim.x * blockDim.x)
        atomicAdd(&cnt[dst[e]], 1);
}

__global__ __launch_bounds__(256) void offsets_kernel(
    const int* __restrict__ cnt, int N, int* __restrict__ offv,
    int* __restrict__ fill, int* __restrict__ csr, int* __restrict__ cursor)
{
    int n = blockIdx.x * blockDim.x + threadIdx.x;
    int lane = threadIdx.x & 63;
    int v = (n < N) ? (cnt[n] + 1) : 0;
    int incl = v;
#pragma unroll
    for (int d = 1; d < 64; d <<= 1) {
        int t = __shfl_up(incl, d);
        if (lane >= d) incl += t;
    }
    int total = __shfl(incl, 63);
    int base = 0;
    if (lane == 63) base = atomicAdd(cursor, total);
    base = __shfl(base, 63);
    if (n < N) {
        int o = base + incl - v;
        offv[n] = o;
        csr[o] = n;   // self loop at slot 0
        fill[n] = 1;
    }
}

__global__ void scatter_kernel(const int* __restrict__ src, const int* __restrict__ dst, int E,
                               const int* __restrict__ offv, int* __restrict__ fill,
                               int* __restrict__ csr)
{
    for (int e = blockIdx.x * blockDim.x + threadIdx.x; e < E; e += gridDim.x * blockDim.x) {
        int d = dst[e];
        int pos = offv[d] + atomicAdd(&fill[d], 1);
        csr[pos] = src[e];
    }
}

// ---------------- GAT layer 1: 8 heads x 8 ch, fused bias + ELU ----------------
__global__ __launch_bounds__(256) void gat1_kernel(
    const float* __restrict__ h1, const float* __restrict__ asn, const float* __restrict__ adn,
    const float* __restrict__ b1, const int* __restrict__ offv, const int* __restrict__ cnt,
    const int* __restrict__ csr, float* __restrict__ h2, int N)
{
    __shared__ float Pl[4][64 * 8];   // per-wave unnormalized softmax probs [edge][head]
    int wv = threadIdx.x >> 6;
    int n = blockIdx.x * 4 + wv;
    if (n >= N) return;
    int lane = threadIdx.x & 63;
    int base = offv[n];
    int deg = cnt[n] + 1;
    int h = lane & 7, j = lane >> 3;
    int hh = lane >> 3;
    float ad_h = adn[n * 8 + h];
    float* P = Pl[wv];
    float acc = 0.f;

    if (deg <= 64) {
        int sreg = csr[base + (lane < deg ? lane : 0)];
        int nch = (deg + 7) >> 3;
        float e_arr[8];
        float mx = -INFINITY;
#pragma unroll
        for (int cch = 0; cch < 8; ++cch) {
            if (cch < nch) {
                int k = cch * 8 + j;
                int s = __shfl(sreg, k);                 // divergent index -> bpermute
                float e = (k < deg) ? lrelu(asn[s * 8 + h] + ad_h) : -INFINITY;
                e_arr[cch] = e;
                mx = fmaxf(mx, e);
            }
        }
        mx = fmaxf(mx, __shfl_xor(mx, 8));
        mx = fmaxf(mx, __shfl_xor(mx, 16));
        mx = fmaxf(mx, __shfl_xor(mx, 32));
        float sm = 0.f;
#pragma unroll
        for (int cch = 0; cch < 8; ++cch) {
            if (cch < nch) {
                int k = cch * 8 + j;
                float p = (k < deg) ? __expf(e_arr[cch] - mx) : 0.f;
                sm += p;
                P[k * 8 + h] = p;
            }
        }
        sm += __shfl_xor(sm, 8);
        sm += __shfl_xor(sm, 16);
        sm += __shfl_xor(sm, 32);
        float rdn = 1.f / (sm + 1e-16f);
        float rdnh = __shfl(rdn, hh);
        int k = 0;
        for (; k + 4 <= deg; k += 4) {
            int s0 = readlane_i(sreg, k), s1 = readlane_i(sreg, k + 1),
                s2 = readlane_i(sreg, k + 2), s3 = readlane_i(sreg, k + 3);
            float p0 = P[(k + 0) * 8 + hh], p1 = P[(k + 1) * 8 + hh],
                  p2 = P[(k + 2) * 8 + hh], p3 = P[(k + 3) * 8 + hh];
            acc += p0 * h1[(size_t)s0 * 64 + lane];
            acc += p1 * h1[(size_t)s1 * 64 + lane];
            acc += p2 * h1[(size_t)s2 * 64 + lane];
            acc += p3 * h1[(size_t)s3 * 64 + lane];
        }
        for (; k < deg; ++k) {
            int s = readlane_i(sreg, k);
            acc += P[k * 8 + hh] * h1[(size_t)s * 64 + lane];
        }
        acc *= rdnh;
    } else {
        // slow fallback (deg > 64): recompute, div hoisted
        float mx = -INFINITY;
        for (int k = j; k < deg; k += 8) {
            int s = csr[base + k];
            mx = fmaxf(mx, lrelu(asn[s * 8 + h] + ad_h));
        }
        mx = fmaxf(mx, __shfl_xor(mx, 8));
        mx = fmaxf(mx, __shfl_xor(mx, 16));
        mx = fmaxf(mx, __shfl_xor(mx, 32));
        float sm = 0.f;
        for (int k = j; k < deg; k += 8) {
            int s = csr[base + k];
            sm += __expf(lrelu(asn[s * 8 + h] + ad_h) - mx);
        }
        sm += __shfl_xor(sm, 8);
        sm += __shfl_xor(sm, 16);
        sm += __shfl_xor(sm, 32);
        float rdn = 1.f / (sm + 1e-16f);
        float mxh = __shfl(mx, hh);
        float rdnh = __shfl(rdn, hh);
        float adhh = adn[n * 8 + hh];
        for (int k = 0; k < deg; ++k) {
            int s = csr[base + k];
            float e = lrelu(asn[s * 8 + hh] + adhh);
            acc += __expf(e - mxh) * h1[(size_t)s * 64 + lane];
        }
        acc *= rdnh;
    }
    float v = acc + b1[lane];
    h2[(size_t)n * 64 + lane] = v > 0.f ? v : __expf(v) - 1.f;  // ELU
}

// ---------------- GAT layer 2: 1 head x 64 ch, fused bias ----------------
__global__ __launch_bounds__(256) void gat2_kernel(
    const float* __restrict__ z, const float* __restrict__ asn, const float* __restrict__ adn,
    const float* __restrict__ b2, const int* __restrict__ offv, const int* __restrict__ cnt,
    const int* __restrict__ csr, float* __restrict__ out, int N)
{
    int n = blockIdx.x * 4 + (threadIdx.x >> 6);
    if (n >= N) return;
    int lane = threadIdx.x & 63;
    int base = offv[n];
    int deg = cnt[n] + 1;
    float ad_n = adn[n];
    float acc = 0.f;
    float rdn;

    if (deg <= 64) {
        int sreg = csr[base + (lane < deg ? lane : 0)];
        float e = (lane < deg) ? lrelu(asn[sreg] + ad_n) : -INFINITY;
        float mx = e;
#pragma unroll
        for (int d = 1; d < 64; d <<= 1) mx = fmaxf(mx, __shfl_xor(mx, d));
        float p = (lane < deg) ? __expf(e - mx) : 0.f;
        float sm = p;
#pragma unroll
        for (int d = 1; d < 64; d <<= 1) sm += __shfl_xor(sm, d);
        rdn = 1.f / (sm + 1e-16f);
        int k = 0;
        for (; k + 4 <= deg; k += 4) {
            int s0 = readlane_i(sreg, k), s1 = readlane_i(sreg, k + 1),
                s2 = readlane_i(sreg, k + 2), s3 = readlane_i(sreg, k + 3);
            float p0 = readlane_f(p, k), p1 = readlane_f(p, k + 1),
                  p2 = readlane_f(p, k + 2), p3 = readlane_f(p, k + 3);
            acc += p0 * z[(size_t)s0 * 64 + lane];
            acc += p1 * z[(size_t)s1 * 64 + lane];
            acc += p2 * z[(size_t)s2 * 64 + lane];
            acc += p3 * z[(size_t)s3 * 64 + lane];
        }
        for (; k < deg; ++k)
            acc += readlane_f(p, k) * z[(size_t)readlane_i(sreg, k) * 64 + lane];
    } else {
        float mx = -INFINITY;
        for (int k = lane; k < deg; k += 64) {
            int s = csr[base + k];
            mx = fmaxf(mx, lrelu(asn[s] + ad_n));
        }
#pragma unroll
        for (int d = 1; d < 64; d <<= 1) mx = fmaxf(mx, __shfl_xor(mx, d));
        float sm = 0.f;
        for (int k = lane; k < deg; k += 64) {
            int s = csr[base + k];
            sm += __expf(lrelu(asn[s] + ad_n) - mx);
        }
#pragma unroll
        for (int d = 1; d < 64; d <<= 1) sm += __shfl_xor(sm, d);
        rdn = 1.f / (sm + 1e-16f);
        for (int k = 0; k < deg; ++k) {
            int s = csr[base + k];
            acc += __expf(lrelu(asn[s] + ad_n) - mx) * z[(size_t)s * 64 + lane];
        }
    }
    out[(size_t)n * 64 + lane] = acc * rdn + b2[lane];
}

// ---------------- decode: sigmoid(dot(z2[q0], z2[q1])) ----------------
__global__ __launch_bounds__(256) void decode_kernel(
    const float* __restrict__ z2, const int* __restrict__ q, int Q, float* __restrict__ out)
{
    int i = blockIdx.x * 4 + (threadIdx.x >> 6);
    if (i >= Q) return;
    int lane = threadIdx.x & 63;
    int a = q[i], b = q[Q + i];
    float v = z2[(size_t)a * 64 + lane] * z2[(size_t)b * 64 + lane];
#pragma unroll
    for (int d = 1; d < 64; d <<= 1) v += __shfl_xor(v, d);
    if (lane == 0) out[i] = 1.f / (1.f + __expf(-v));
}

extern "C" void kernel_launch(void* const* d_in, const int* in_sizes, int n_in,
                              void* d_out, int out_size, void* d_ws, size_t ws_size,
                              hipStream_t stream)
{
    const float* x   = (const float*)d_in[0];
    const int*   ei  = (const int*)d_in[1];
    const int*   qe  = (const int*)d_in[2];
    const float* W1  = (const float*)d_in[3];
    const float* as1 = (const float*)d_in[4];
    const float* ad1 = (const float*)d_in[5];
    const float* b1  = (const float*)d_in[6];
    const float* W2  = (const float*)d_in[7];
    const float* as2 = (const float*)d_in[8];
    const float* ad2 = (const float*)d_in[9];
    const float* b2  = (const float*)d_in[10];

    const int N = in_sizes[0] / 128;
    const int E = in_sizes[1] / 2;
    const int Q = in_sizes[2] / 2;

    float* out = (float*)d_out;

    char* ws = (char*)d_ws;
    size_t o = 0;
    auto alloc = [&](size_t bytes) -> void* {
        void* p = ws + o;
        o += (bytes + 255) & ~(size_t)255;
        return p;
    };
    float* bufA  = (float*)alloc((size_t)N * 64 * 4);  // h1, later z
    float* bufB  = (float*)alloc((size_t)N * 64 * 4);  // h2, later z2
    float* asn1  = (float*)alloc((size_t)N * 8 * 4);
    float* adn1  = (float*)alloc((size_t)N * 8 * 4);
    float* asn2  = (float*)alloc((size_t)N * 4);
    float* adn2  = (float*)alloc((size_t)N * 4);
    int*   cnt   = (int*)alloc((size_t)N * 4);
    int*   offv  = (int*)alloc((size_t)N * 4);
    int*   fill  = (int*)alloc((size_t)N * 4);
    int*   cursor= (int*)alloc(256);
    int*   csr   = (int*)alloc((size_t)(E + N) * 4);

    const int* esrc = ei;
    const int* edst = ei + E;

    hipMemsetAsync(cnt, 0, (size_t)N * 4, stream);
    hipMemsetAsync(cursor, 0, 4, stream);

    int nodeBlocks4 = (N + 3) / 4;
    int rowBlocks8  = (N + 7) / 8;
    int edgeBlocks  = (E + 255) / 256;
    int nodeBlocks  = (N + 255) / 256;

    gemm1_kernel<<<rowBlocks8, 256, 0, stream>>>(x, W1, as1, ad1, bufA, asn1, adn1, N);
    count_kernel<<<edgeBlocks, 256, 0, stream>>>(edst, E, cnt);
    offsets_kernel<<<nodeBlocks, 256, 0, stream>>>(cnt, N, offv, fill, csr, cursor);
    scatter_kernel<<<edgeBlocks, 256, 0, stream>>>(esrc, edst, E, offv, fill, csr);
    gat1_kernel<<<nodeBlocks4, 256, 0, stream>>>(bufA, asn1, adn1, b1, offv, cnt, csr, bufB, N);
    gemm2_kernel<<<rowBlocks8, 256, 0, stream>>>(bufB, W2, as2, ad2, bufA, asn2, adn2, N);
    gat2_kernel<<<nodeBlocks4, 256, 0, stream>>>(bufA, asn2, adn2, b2, offv, cnt, csr, bufB, N);
    decode_kernel<<<(Q + 3) / 4, 256, 0, stream>>>(bufB, qe, Q, out);
}

// Round 4
// 525.292 us; speedup vs baseline: 1.6795x; 1.0856x over previous
//
#include <hip/hip_runtime.h>
#include <math.h>

constexpr float NEG_SLOPE = 0.2f;

__device__ __forceinline__ float lrelu(float x) { return x > 0.f ? x : NEG_SLOPE * x; }

__device__ __forceinline__ float readlane_f(float v, int l) {
    return __uint_as_float(__builtin_amdgcn_readlane(__float_as_uint(v), l));
}
__device__ __forceinline__ int readlane_i(int v, int l) {
    return __builtin_amdgcn_readlane(v, l);
}

#define MAC16(av, bv) \
    acc[0][0] += av.x*bv.x; acc[0][1] += av.x*bv.y; acc[0][2] += av.x*bv.z; acc[0][3] += av.x*bv.w; \
    acc[1][0] += av.y*bv.x; acc[1][1] += av.y*bv.y; acc[1][2] += av.y*bv.z; acc[1][3] += av.y*bv.w; \
    acc[2][0] += av.z*bv.x; acc[2][1] += av.z*bv.y; acc[2][2] += av.z*bv.z; acc[2][3] += av.z*bv.w; \
    acc[3][0] += av.w*bv.x; acc[3][1] += av.w*bv.y; acc[3][2] += av.w*bv.z; acc[3][3] += av.w*bv.w;

// ---------------- GEMM1: h1 = x @ W1 (64x64 tile, 4x4/thread) + per-head alphas ----------------
__global__ __launch_bounds__(256) void gemm1_kernel(
    const float* __restrict__ X, const float* __restrict__ W,
    const float* __restrict__ a_s, const float* __restrict__ a_d,
    float* __restrict__ H, float* __restrict__ asn, float* __restrict__ adn, int N)
{
    __shared__ float At[128 * 64];
    __shared__ float Bs[128 * 64];
    const int tid = threadIdx.x;
    const int r_base = blockIdx.x * 64;
    {
        const float4* W4 = (const float4*)W;
        float4* B4 = (float4*)Bs;
#pragma unroll
        for (int it = 0; it < 8; ++it) B4[tid + it * 256] = W4[tid + it * 256];
    }
    {
        const float4* X4 = (const float4*)X;
#pragma unroll
        for (int it = 0; it < 2; ++it) {
            int t = tid + it * 256;          // 512 tasks: 4x4 block transpose
            int rg = t & 15, cg = t >> 4;    // rg: row quad, cg: k quad (0..31)
            float4 rw[4];
#pragma unroll
            for (int j = 0; j < 4; ++j) {
                int r = r_base + rg * 4 + j;
                rw[j] = (r < N) ? X4[(size_t)r * 32 + cg] : make_float4(0.f, 0.f, 0.f, 0.f);
            }
            int rsw = 4 * (rg ^ (cg & 15));
            int k0 = cg * 4;
            *(float4*)&At[(k0    ) * 64 + rsw] = make_float4(rw[0].x, rw[1].x, rw[2].x, rw[3].x);
            *(float4*)&At[(k0 + 1) * 64 + rsw] = make_float4(rw[0].y, rw[1].y, rw[2].y, rw[3].y);
            *(float4*)&At[(k0 + 2) * 64 + rsw] = make_float4(rw[0].z, rw[1].z, rw[2].z, rw[3].z);
            *(float4*)&At[(k0 + 3) * 64 + rsw] = make_float4(rw[0].w, rw[1].w, rw[2].w, rw[3].w);
        }
    }
    __syncthreads();
    const int m  = tid & 15;
    const int ci = (tid >> 4) * 4;
    float acc[4][4] = {};
#pragma unroll 4
    for (int kq = 0; kq < 32; ++kq) {
        int aoff = kq * 256 + 4 * (m ^ (kq & 15));
        int boff = kq * 256 + ci;
        float4 a0 = *(const float4*)&At[aoff];
        float4 a1 = *(const float4*)&At[aoff + 64];
        float4 a2 = *(const float4*)&At[aoff + 128];
        float4 a3 = *(const float4*)&At[aoff + 192];
        float4 b0 = *(const float4*)&Bs[boff];
        float4 b1 = *(const float4*)&Bs[boff + 64];
        float4 b2 = *(const float4*)&Bs[boff + 128];
        float4 b3 = *(const float4*)&Bs[boff + 192];
        MAC16(a0, b0); MAC16(a1, b1); MAC16(a2, b2); MAC16(a3, b3);
    }
    float asv[4] = {a_s[ci], a_s[ci + 1], a_s[ci + 2], a_s[ci + 3]};
    float adv[4] = {a_d[ci], a_d[ci + 1], a_d[ci + 2], a_d[ci + 3]};
    int head = ci >> 3;
    bool owner = ((tid >> 4) & 1) == 0;
#pragma unroll
    for (int j = 0; j < 4; ++j) {
        int r = r_base + m * 4 + j;
        if (r < N) *(float4*)&H[(size_t)r * 64 + ci] =
            make_float4(acc[j][0], acc[j][1], acc[j][2], acc[j][3]);
        float ps = acc[j][0]*asv[0] + acc[j][1]*asv[1] + acc[j][2]*asv[2] + acc[j][3]*asv[3];
        float pd = acc[j][0]*adv[0] + acc[j][1]*adv[1] + acc[j][2]*adv[2] + acc[j][3]*adv[3];
        ps += __shfl_xor(ps, 16);
        pd += __shfl_xor(pd, 16);
        if (owner && r < N) { asn[r * 8 + head] = ps; adn[r * 8 + head] = pd; }
    }
}

// ---------------- GEMM2: z = h2 @ W2 (64x64 tile) + scalar alphas ----------------
__global__ __launch_bounds__(256) void gemm2_kernel(
    const float* __restrict__ X, const float* __restrict__ W,
    const float* __restrict__ a_s, const float* __restrict__ a_d,
    float* __restrict__ H, float* __restrict__ asn, float* __restrict__ adn, int N)
{
    __shared__ float At[64 * 64];
    __shared__ float Bs[64 * 64];
    __shared__ float Ps[4][16][4], Pd[4][16][4];
    const int tid = threadIdx.x;
    const int r_base = blockIdx.x * 64;
    {
        const float4* W4 = (const float4*)W;
        float4* B4 = (float4*)Bs;
#pragma unroll
        for (int it = 0; it < 4; ++it) B4[tid + it * 256] = W4[tid + it * 256];
    }
    {
        const float4* X4 = (const float4*)X;
        int rg = tid & 15, cg = tid >> 4;    // cg 0..15
        float4 rw[4];
#pragma unroll
        for (int j = 0; j < 4; ++j) {
            int r = r_base + rg * 4 + j;
            rw[j] = (r < N) ? X4[(size_t)r * 16 + cg] : make_float4(0.f, 0.f, 0.f, 0.f);
        }
        int rsw = 4 * (rg ^ (cg & 15));
        int k0 = cg * 4;
        *(float4*)&At[(k0    ) * 64 + rsw] = make_float4(rw[0].x, rw[1].x, rw[2].x, rw[3].x);
        *(float4*)&At[(k0 + 1) * 64 + rsw] = make_float4(rw[0].y, rw[1].y, rw[2].y, rw[3].y);
        *(float4*)&At[(k0 + 2) * 64 + rsw] = make_float4(rw[0].z, rw[1].z, rw[2].z, rw[3].z);
        *(float4*)&At[(k0 + 3) * 64 + rsw] = make_float4(rw[0].w, rw[1].w, rw[2].w, rw[3].w);
    }
    __syncthreads();
    const int m  = tid & 15;
    const int ci = (tid >> 4) * 4;
    float acc[4][4] = {};
#pragma unroll 4
    for (int kq = 0; kq < 16; ++kq) {
        int aoff = kq * 256 + 4 * (m ^ (kq & 15));
        int boff = kq * 256 + ci;
        float4 a0 = *(const float4*)&At[aoff];
        float4 a1 = *(const float4*)&At[aoff + 64];
        float4 a2 = *(const float4*)&At[aoff + 128];
        float4 a3 = *(const float4*)&At[aoff + 192];
        float4 b0 = *(const float4*)&Bs[boff];
        float4 b1 = *(const float4*)&Bs[boff + 64];
        float4 b2 = *(const float4*)&Bs[boff + 128];
        float4 b3 = *(const float4*)&Bs[boff + 192];
        MAC16(a0, b0); MAC16(a1, b1); MAC16(a2, b2); MAC16(a3, b3);
    }
    float asv[4] = {a_s[ci], a_s[ci + 1], a_s[ci + 2], a_s[ci + 3]};
    float adv[4] = {a_d[ci], a_d[ci + 1], a_d[ci + 2], a_d[ci + 3]};
    int w = tid >> 6;
    float ps[4], pd[4];
#pragma unroll
    for (int j = 0; j < 4; ++j) {
        int r = r_base + m * 4 + j;
        if (r < N) *(float4*)&H[(size_t)r * 64 + ci] =
            make_float4(acc[j][0], acc[j][1], acc[j][2], acc[j][3]);
        ps[j] = acc[j][0]*asv[0] + acc[j][1]*asv[1] + acc[j][2]*asv[2] + acc[j][3]*asv[3];
        pd[j] = acc[j][0]*adv[0] + acc[j][1]*adv[1] + acc[j][2]*adv[2] + acc[j][3]*adv[3];
        ps[j] += __shfl_xor(ps[j], 16); ps[j] += __shfl_xor(ps[j], 32);
        pd[j] += __shfl_xor(pd[j], 16); pd[j] += __shfl_xor(pd[j], 32);
    }
    if (((tid >> 4) & 3) == 0) {
#pragma unroll
        for (int j = 0; j < 4; ++j) { Ps[w][m][j] = ps[j]; Pd[w][m][j] = pd[j]; }
    }
    __syncthreads();
    if (tid < 64) {
        int r = r_base + tid;
        if (r < N) {
            int mm = tid >> 2, jj = tid & 3;
            asn[r] = Ps[0][mm][jj] + Ps[1][mm][jj] + Ps[2][mm][jj] + Ps[3][mm][jj];
            adn[r] = Pd[0][mm][jj] + Pd[1][mm][jj] + Pd[2][mm][jj] + Pd[3][mm][jj];
        }
    }
}

// ---------------- CSR build (round-2 proven version) ----------------
__global__ void count_kernel(const int* __restrict__ dst, int E, int* __restrict__ cnt)
{
    for (int e = blockIdx.x * blockDim.x + threadIdx.x; e < E; e += gridDim.x * blockDim.x)
        atomicAdd(&cnt[dst[e]], 1);
}

__global__ __launch_bounds__(256) void offsets_kernel(
    const int* __restrict__ cnt, int N, int* __restrict__ offv,
    int* __restrict__ fill, int* __restrict__ csr, int* __restrict__ cursor)
{
    int n = blockIdx.x * blockDim.x + threadIdx.x;
    int lane = threadIdx.x & 63;
    int v = (n < N) ? (cnt[n] + 1) : 0;
    int incl = v;
#pragma unroll
    for (int d = 1; d < 64; d <<= 1) {
        int t = __shfl_up(incl, d);
        if (lane >= d) incl += t;
    }
    int total = __shfl(incl, 63);
    int base = 0;
    if (lane == 63) base = atomicAdd(cursor, total);
    base = __shfl(base, 63);
    if (n < N) {
        int o = base + incl - v;
        offv[n] = o;
        csr[o] = n;   // self loop at slot 0
        fill[n] = 1;
    }
}

__global__ void scatter_kernel(const int* __restrict__ src, const int* __restrict__ dst, int E,
                               const int* __restrict__ offv, int* __restrict__ fill,
                               int* __restrict__ csr)
{
    for (int e = blockIdx.x * blockDim.x + threadIdx.x; e < E; e += gridDim.x * blockDim.x) {
        int d = dst[e];
        int pos = offv[d] + atomicAdd(&fill[d], 1);
        csr[pos] = src[e];
    }
}

// ---------------- GAT layer 1: 8 heads x 8 ch, fused bias + ELU ----------------
__global__ __launch_bounds__(256) void gat1_kernel(
    const float* __restrict__ h1, const float* __restrict__ asn, const float* __restrict__ adn,
    const float* __restrict__ b1, const int* __restrict__ offv, const int* __restrict__ cnt,
    const int* __restrict__ csr, float* __restrict__ h2, int N)
{
    __shared__ float Pl[4][64 * 8];
    int wv = threadIdx.x >> 6;
    int n = blockIdx.x * 4 + wv;
    if (n >= N) return;
    int lane = threadIdx.x & 63;
    int base = offv[n];
    int deg = cnt[n] + 1;
    int h = lane & 7, j = lane >> 3;
    int hh = lane >> 3;
    float ad_h = adn[n * 8 + h];
    float* P = Pl[wv];
    float acc = 0.f;

    if (deg <= 64) {
        int sreg = csr[base + (lane < deg ? lane : 0)];
        int nch = (deg + 7) >> 3;
        float e_arr[8];
        float mx = -INFINITY;
#pragma unroll
        for (int cch = 0; cch < 8; ++cch) {
            if (cch < nch) {
                int k = cch * 8 + j;
                int s = __shfl(sreg, k);
                float e = (k < deg) ? lrelu(asn[s * 8 + h] + ad_h) : -INFINITY;
                e_arr[cch] = e;
                mx = fmaxf(mx, e);
            }
        }
        mx = fmaxf(mx, __shfl_xor(mx, 8));
        mx = fmaxf(mx, __shfl_xor(mx, 16));
        mx = fmaxf(mx, __shfl_xor(mx, 32));
        float sm = 0.f;
#pragma unroll
        for (int cch = 0; cch < 8; ++cch) {
            if (cch < nch) {
                int k = cch * 8 + j;
                float p = (k < deg) ? __expf(e_arr[cch] - mx) : 0.f;
                sm += p;
                P[k * 8 + h] = p;
            }
        }
        sm += __shfl_xor(sm, 8);
        sm += __shfl_xor(sm, 16);
        sm += __shfl_xor(sm, 32);
        float rdn = 1.f / (sm + 1e-16f);
        float rdnh = __shfl(rdn, hh);
        int k = 0;
        for (; k + 4 <= deg; k += 4) {
            int s0 = readlane_i(sreg, k), s1 = readlane_i(sreg, k + 1),
                s2 = readlane_i(sreg, k + 2), s3 = readlane_i(sreg, k + 3);
            float p0 = P[(k + 0) * 8 + hh], p1 = P[(k + 1) * 8 + hh],
                  p2 = P[(k + 2) * 8 + hh], p3 = P[(k + 3) * 8 + hh];
            acc += p0 * h1[(size_t)s0 * 64 + lane];
            acc += p1 * h1[(size_t)s1 * 64 + lane];
            acc += p2 * h1[(size_t)s2 * 64 + lane];
            acc += p3 * h1[(size_t)s3 * 64 + lane];
        }
        for (; k < deg; ++k) {
            int s = readlane_i(sreg, k);
            acc += P[k * 8 + hh] * h1[(size_t)s * 64 + lane];
        }
        acc *= rdnh;
    } else {
        float mx = -INFINITY;
        for (int k = j; k < deg; k += 8) {
            int s = csr[base + k];
            mx = fmaxf(mx, lrelu(asn[s * 8 + h] + ad_h));
        }
        mx = fmaxf(mx, __shfl_xor(mx, 8));
        mx = fmaxf(mx, __shfl_xor(mx, 16));
        mx = fmaxf(mx, __shfl_xor(mx, 32));
        float sm = 0.f;
        for (int k = j; k < deg; k += 8) {
            int s = csr[base + k];
            sm += __expf(lrelu(asn[s * 8 + h] + ad_h) - mx);
        }
        sm += __shfl_xor(sm, 8);
        sm += __shfl_xor(sm, 16);
        sm += __shfl_xor(sm, 32);
        float rdn = 1.f / (sm + 1e-16f);
        float mxh = __shfl(mx, hh);
        float rdnh = __shfl(rdn, hh);
        float adhh = adn[n * 8 + hh];
        for (int k = 0; k < deg; ++k) {
            int s = csr[base + k];
            float e = lrelu(asn[s * 8 + hh] + adhh);
            acc += __expf(e - mxh) * h1[(size_t)s * 64 + lane];
        }
        acc *= rdnh;
    }
    float v = acc + b1[lane];
    h2[(size_t)n * 64 + lane] = v > 0.f ? v : __expf(v) - 1.f;
}

// ---------------- GAT layer 2: 1 head x 64 ch, fused bias ----------------
__global__ __launch_bounds__(256) void gat2_kernel(
    const float* __restrict__ z, const float* __restrict__ asn, const float* __restrict__ adn,
    const float* __restrict__ b2, const int* __restrict__ offv, const int* __restrict__ cnt,
    const int* __restrict__ csr, float* __restrict__ out, int N)
{
    int n = blockIdx.x * 4 + (threadIdx.x >> 6);
    if (n >= N) return;
    int lane = threadIdx.x & 63;
    int base = offv[n];
    int deg = cnt[n] + 1;
    float ad_n = adn[n];
    float acc = 0.f;
    float rdn;

    if (deg <= 64) {
        int sreg = csr[base + (lane < deg ? lane : 0)];
        float e = (lane < deg) ? lrelu(asn[sreg] + ad_n) : -INFINITY;
        float mx = e;
#pragma unroll
        for (int d = 1; d < 64; d <<= 1) mx = fmaxf(mx, __shfl_xor(mx, d));
        float p = (lane < deg) ? __expf(e - mx) : 0.f;
        float sm = p;
#pragma unroll
        for (int d = 1; d < 64; d <<= 1) sm += __shfl_xor(sm, d);
        rdn = 1.f / (sm + 1e-16f);
        int k = 0;
        for (; k + 4 <= deg; k += 4) {
            int s0 = readlane_i(sreg, k), s1 = readlane_i(sreg, k + 1),
                s2 = readlane_i(sreg, k + 2), s3 = readlane_i(sreg, k + 3);
            float p0 = readlane_f(p, k), p1 = readlane_f(p, k + 1),
                  p2 = readlane_f(p, k + 2), p3 = readlane_f(p, k + 3);
            acc += p0 * z[(size_t)s0 * 64 + lane];
            acc += p1 * z[(size_t)s1 * 64 + lane];
            acc += p2 * z[(size_t)s2 * 64 + lane];
            acc += p3 * z[(size_t)s3 * 64 + lane];
        }
        for (; k < deg; ++k)
            acc += readlane_f(p, k) * z[(size_t)readlane_i(sreg, k) * 64 + lane];
    } else {
        float mx = -INFINITY;
        for (int k = lane; k < deg; k += 64) {
            int s = csr[base + k];
            mx = fmaxf(mx, lrelu(asn[s] + ad_n));
        }
#pragma unroll
        for (int d = 1; d < 64; d <<= 1) mx = fmaxf(mx, __shfl_xor(mx, d));
        float sm = 0.f;
        for (int k = lane; k < deg; k += 64) {
            int s = csr[base + k];
            sm += __expf(lrelu(asn[s] + ad_n) - mx);
        }
#pragma unroll
        for (int d = 1; d < 64; d <<= 1) sm += __shfl_xor(sm, d);
        rdn = 1.f / (sm + 1e-16f);
        for (int k = 0; k < deg; ++k) {
            int s = csr[base + k];
            acc += __expf(lrelu(asn[s] + ad_n) - mx) * z[(size_t)s * 64 + lane];
        }
    }
    out[(size_t)n * 64 + lane] = acc * rdn + b2[lane];
}

// ---------------- decode ----------------
__global__ __launch_bounds__(256) void decode_kernel(
    const float* __restrict__ z2, const int* __restrict__ q, int Q, float* __restrict__ out)
{
    int i = blockIdx.x * 4 + (threadIdx.x >> 6);
    if (i >= Q) return;
    int lane = threadIdx.x & 63;
    int a = q[i], b = q[Q + i];
    float v = z2[(size_t)a * 64 + lane] * z2[(size_t)b * 64 + lane];
#pragma unroll
    for (int d = 1; d < 64; d <<= 1) v += __shfl_xor(v, d);
    if (lane == 0) out[i] = 1.f / (1.f + __expf(-v));
}

extern "C" void kernel_launch(void* const* d_in, const int* in_sizes, int n_in,
                              void* d_out, int out_size, void* d_ws, size_t ws_size,
                              hipStream_t stream)
{
    const float* x   = (const float*)d_in[0];
    const int*   ei  = (const int*)d_in[1];
    const int*   qe  = (const int*)d_in[2];
    const float* W1  = (const float*)d_in[3];
    const float* as1 = (const float*)d_in[4];
    const float* ad1 = (const float*)d_in[5];
    const float* b1  = (const float*)d_in[6];
    const float* W2  = (const float*)d_in[7];
    const float* as2 = (const float*)d_in[8];
    const float* ad2 = (const float*)d_in[9];
    const float* b2  = (const float*)d_in[10];

    const int N = in_sizes[0] / 128;
    const int E = in_sizes[1] / 2;
    const int Q = in_sizes[2] / 2;

    float* out = (float*)d_out;

    char* ws = (char*)d_ws;
    size_t o = 0;
    auto alloc = [&](size_t bytes) -> void* {
        void* p = ws + o;
        o += (bytes + 255) & ~(size_t)255;
        return p;
    };
    float* bufA  = (float*)alloc((size_t)N * 64 * 4);  // h1, later z
    float* bufB  = (float*)alloc((size_t)N * 64 * 4);  // h2, later z2
    float* asn1  = (float*)alloc((size_t)N * 8 * 4);
    float* adn1  = (float*)alloc((size_t)N * 8 * 4);
    float* asn2  = (float*)alloc((size_t)N * 4);
    float* adn2  = (float*)alloc((size_t)N * 4);
    int*   cnt   = (int*)alloc((size_t)N * 4);
    int*   offv  = (int*)alloc((size_t)N * 4);
    int*   fill  = (int*)alloc((size_t)N * 4);
    int*   cursor= (int*)alloc(256);
    int*   csr   = (int*)alloc((size_t)(E + N) * 4);

    const int* esrc = ei;
    const int* edst = ei + E;

    hipMemsetAsync(cnt, 0, (size_t)N * 4, stream);
    hipMemsetAsync(cursor, 0, 4, stream);

    int nodeBlocks4 = (N + 3) / 4;
    int tileBlocks  = (N + 63) / 64;
    int edgeBlocks  = (E + 255) / 256;
    int nodeBlocks  = (N + 255) / 256;

    gemm1_kernel<<<tileBlocks, 256, 0, stream>>>(x, W1, as1, ad1, bufA, asn1, adn1, N);
    count_kernel<<<edgeBlocks, 256, 0, stream>>>(edst, E, cnt);
    offsets_kernel<<<nodeBlocks, 256, 0, stream>>>(cnt, N, offv, fill, csr, cursor);
    scatter_kernel<<<edgeBlocks, 256, 0, stream>>>(esrc, edst, E, offv, fill, csr);
    gat1_kernel<<<nodeBlocks4, 256, 0, stream>>>(bufA, asn1, adn1, b1, offv, cnt, csr, bufB, N);
    gemm2_kernel<<<tileBlocks, 256, 0, stream>>>(bufB, W2, as2, ad2, bufA, asn2, adn2, N);
    gat2_kernel<<<nodeBlocks4, 256, 0, stream>>>(bufA, asn2, adn2, b2, offv, cnt, csr, bufB, N);
    decode_kernel<<<(Q + 3) / 4, 256, 0, stream>>>(bufB, qe, Q, out);
}

// Round 5
// 508.738 us; speedup vs baseline: 1.7341x; 1.0325x over previous
//
#include <hip/hip_runtime.h>
#include <math.h>

constexpr float NEG_SLOPE = 0.2f;

__device__ __forceinline__ float lrelu(float x) { return x > 0.f ? x : NEG_SLOPE * x; }

__device__ __forceinline__ float readlane_f(float v, int l) {
    return __uint_as_float(__builtin_amdgcn_readlane(__float_as_uint(v), l));
}
__device__ __forceinline__ int readlane_i(int v, int l) {
    return __builtin_amdgcn_readlane(v, l);
}

#define MAC16(av, bv) \
    acc[0][0] += av.x*bv.x; acc[0][1] += av.x*bv.y; acc[0][2] += av.x*bv.z; acc[0][3] += av.x*bv.w; \
    acc[1][0] += av.y*bv.x; acc[1][1] += av.y*bv.y; acc[1][2] += av.y*bv.z; acc[1][3] += av.y*bv.w; \
    acc[2][0] += av.z*bv.x; acc[2][1] += av.z*bv.y; acc[2][2] += av.z*bv.z; acc[2][3] += av.z*bv.w; \
    acc[3][0] += av.w*bv.x; acc[3][1] += av.w*bv.y; acc[3][2] += av.w*bv.z; acc[3][3] += av.w*bv.w;

// ---------------- GEMM1: h1 = x @ W1 (64x64 tile, 4x4/thread) ----------------
// Output rows stride 80: [0..63]=h, [64..71]=alpha_src per head. alpha_dst -> adn[N,8].
__global__ __launch_bounds__(256) void gemm1_kernel(
    const float* __restrict__ X, const float* __restrict__ W,
    const float* __restrict__ a_s, const float* __restrict__ a_d,
    float* __restrict__ H, float* __restrict__ adn, int N)
{
    __shared__ float At[128 * 64];
    __shared__ float Bs[128 * 64];
    const int tid = threadIdx.x;
    const int r_base = blockIdx.x * 64;
    {
        const float4* W4 = (const float4*)W;
        float4* B4 = (float4*)Bs;
#pragma unroll
        for (int it = 0; it < 8; ++it) B4[tid + it * 256] = W4[tid + it * 256];
    }
    {
        const float4* X4 = (const float4*)X;
#pragma unroll
        for (int it = 0; it < 2; ++it) {
            int t = tid + it * 256;          // 512 tasks: 4x4 block transpose
            int rg = t & 15, cg = t >> 4;    // rg: row quad, cg: k quad (0..31)
            float4 rw[4];
#pragma unroll
            for (int j = 0; j < 4; ++j) {
                int r = r_base + rg * 4 + j;
                rw[j] = (r < N) ? X4[(size_t)r * 32 + cg] : make_float4(0.f, 0.f, 0.f, 0.f);
            }
            int rsw = 4 * (rg ^ (cg & 15));
            int k0 = cg * 4;
            *(float4*)&At[(k0    ) * 64 + rsw] = make_float4(rw[0].x, rw[1].x, rw[2].x, rw[3].x);
            *(float4*)&At[(k0 + 1) * 64 + rsw] = make_float4(rw[0].y, rw[1].y, rw[2].y, rw[3].y);
            *(float4*)&At[(k0 + 2) * 64 + rsw] = make_float4(rw[0].z, rw[1].z, rw[2].z, rw[3].z);
            *(float4*)&At[(k0 + 3) * 64 + rsw] = make_float4(rw[0].w, rw[1].w, rw[2].w, rw[3].w);
        }
    }
    __syncthreads();
    const int m  = tid & 15;
    const int ci = (tid >> 4) * 4;
    float acc[4][4] = {};
#pragma unroll 4
    for (int kq = 0; kq < 32; ++kq) {
        int aoff = kq * 256 + 4 * (m ^ (kq & 15));
        int boff = kq * 256 + ci;
        float4 a0 = *(const float4*)&At[aoff];
        float4 a1 = *(const float4*)&At[aoff + 64];
        float4 a2 = *(const float4*)&At[aoff + 128];
        float4 a3 = *(const float4*)&At[aoff + 192];
        float4 b0 = *(const float4*)&Bs[boff];
        float4 b1 = *(const float4*)&Bs[boff + 64];
        float4 b2 = *(const float4*)&Bs[boff + 128];
        float4 b3 = *(const float4*)&Bs[boff + 192];
        MAC16(a0, b0); MAC16(a1, b1); MAC16(a2, b2); MAC16(a3, b3);
    }
    float asv[4] = {a_s[ci], a_s[ci + 1], a_s[ci + 2], a_s[ci + 3]};
    float adv[4] = {a_d[ci], a_d[ci + 1], a_d[ci + 2], a_d[ci + 3]};
    int head = ci >> 3;
    bool owner = ((tid >> 4) & 1) == 0;
#pragma unroll
    for (int j = 0; j < 4; ++j) {
        int r = r_base + m * 4 + j;
        if (r < N) *(float4*)&H[(size_t)r * 80 + ci] =
            make_float4(acc[j][0], acc[j][1], acc[j][2], acc[j][3]);
        float ps = acc[j][0]*asv[0] + acc[j][1]*asv[1] + acc[j][2]*asv[2] + acc[j][3]*asv[3];
        float pd = acc[j][0]*adv[0] + acc[j][1]*adv[1] + acc[j][2]*adv[2] + acc[j][3]*adv[3];
        ps += __shfl_xor(ps, 16);
        pd += __shfl_xor(pd, 16);
        if (owner && r < N) { H[(size_t)r * 80 + 64 + head] = ps; adn[r * 8 + head] = pd; }
    }
}

// ---------------- GEMM2: z = h2 @ W2 (64x64 tile) ----------------
// X dense stride 64; output rows stride 80: [0..63]=z, [64]=alpha_src. alpha_dst -> adn[N].
__global__ __launch_bounds__(256) void gemm2_kernel(
    const float* __restrict__ X, const float* __restrict__ W,
    const float* __restrict__ a_s, const float* __restrict__ a_d,
    float* __restrict__ H, float* __restrict__ adn, int N)
{
    __shared__ float At[64 * 64];
    __shared__ float Bs[64 * 64];
    __shared__ float Ps[4][16][4], Pd[4][16][4];
    const int tid = threadIdx.x;
    const int r_base = blockIdx.x * 64;
    {
        const float4* W4 = (const float4*)W;
        float4* B4 = (float4*)Bs;
#pragma unroll
        for (int it = 0; it < 4; ++it) B4[tid + it * 256] = W4[tid + it * 256];
    }
    {
        const float4* X4 = (const float4*)X;
        int rg = tid & 15, cg = tid >> 4;    // cg 0..15
        float4 rw[4];
#pragma unroll
        for (int j = 0; j < 4; ++j) {
            int r = r_base + rg * 4 + j;
            rw[j] = (r < N) ? X4[(size_t)r * 16 + cg] : make_float4(0.f, 0.f, 0.f, 0.f);
        }
        int rsw = 4 * (rg ^ (cg & 15));
        int k0 = cg * 4;
        *(float4*)&At[(k0    ) * 64 + rsw] = make_float4(rw[0].x, rw[1].x, rw[2].x, rw[3].x);
        *(float4*)&At[(k0 + 1) * 64 + rsw] = make_float4(rw[0].y, rw[1].y, rw[2].y, rw[3].y);
        *(float4*)&At[(k0 + 2) * 64 + rsw] = make_float4(rw[0].z, rw[1].z, rw[2].z, rw[3].z);
        *(float4*)&At[(k0 + 3) * 64 + rsw] = make_float4(rw[0].w, rw[1].w, rw[2].w, rw[3].w);
    }
    __syncthreads();
    const int m  = tid & 15;
    const int ci = (tid >> 4) * 4;
    float acc[4][4] = {};
#pragma unroll 4
    for (int kq = 0; kq < 16; ++kq) {
        int aoff = kq * 256 + 4 * (m ^ (kq & 15));
        int boff = kq * 256 + ci;
        float4 a0 = *(const float4*)&At[aoff];
        float4 a1 = *(const float4*)&At[aoff + 64];
        float4 a2 = *(const float4*)&At[aoff + 128];
        float4 a3 = *(const float4*)&At[aoff + 192];
        float4 b0 = *(const float4*)&Bs[boff];
        float4 b1 = *(const float4*)&Bs[boff + 64];
        float4 b2 = *(const float4*)&Bs[boff + 128];
        float4 b3 = *(const float4*)&Bs[boff + 192];
        MAC16(a0, b0); MAC16(a1, b1); MAC16(a2, b2); MAC16(a3, b3);
    }
    float asv[4] = {a_s[ci], a_s[ci + 1], a_s[ci + 2], a_s[ci + 3]};
    float adv[4] = {a_d[ci], a_d[ci + 1], a_d[ci + 2], a_d[ci + 3]};
    int w = tid >> 6;
    float ps[4], pd[4];
#pragma unroll
    for (int j = 0; j < 4; ++j) {
        int r = r_base + m * 4 + j;
        if (r < N) *(float4*)&H[(size_t)r * 80 + ci] =
            make_float4(acc[j][0], acc[j][1], acc[j][2], acc[j][3]);
        ps[j] = acc[j][0]*asv[0] + acc[j][1]*asv[1] + acc[j][2]*asv[2] + acc[j][3]*asv[3];
        pd[j] = acc[j][0]*adv[0] + acc[j][1]*adv[1] + acc[j][2]*adv[2] + acc[j][3]*adv[3];
        ps[j] += __shfl_xor(ps[j], 16); ps[j] += __shfl_xor(ps[j], 32);
        pd[j] += __shfl_xor(pd[j], 16); pd[j] += __shfl_xor(pd[j], 32);
    }
    if (((tid >> 4) & 3) == 0) {
#pragma unroll
        for (int j = 0; j < 4; ++j) { Ps[w][m][j] = ps[j]; Pd[w][m][j] = pd[j]; }
    }
    __syncthreads();
    if (tid < 64) {
        int r = r_base + tid;
        if (r < N) {
            int mm = tid >> 2, jj = tid & 3;
            H[(size_t)r * 80 + 64] = Ps[0][mm][jj] + Ps[1][mm][jj] + Ps[2][mm][jj] + Ps[3][mm][jj];
            adn[r] = Pd[0][mm][jj] + Pd[1][mm][jj] + Pd[2][mm][jj] + Pd[3][mm][jj];
        }
    }
}

// ---------------- CSR build (proven replay-safe version) ----------------
__global__ void count_kernel(const int* __restrict__ dst, int E, int* __restrict__ cnt)
{
    for (int e = blockIdx.x * blockDim.x + threadIdx.x; e < E; e += gridDim.x * blockDim.x)
        atomicAdd(&cnt[dst[e]], 1);
}

__global__ __launch_bounds__(256) void offsets_kernel(
    const int* __restrict__ cnt, int N, int* __restrict__ offv,
    int* __restrict__ fill, int* __restrict__ csr, int* __restrict__ cursor)
{
    int n = blockIdx.x * blockDim.x + threadIdx.x;
    int lane = threadIdx.x & 63;
    int v = (n < N) ? (cnt[n] + 1) : 0;
    int incl = v;
#pragma unroll
    for (int d = 1; d < 64; d <<= 1) {
        int t = __shfl_up(incl, d);
        if (lane >= d) incl += t;
    }
    int total = __shfl(incl, 63);
    int base = 0;
    if (lane == 63) base = atomicAdd(cursor, total);
    base = __shfl(base, 63);
    if (n < N) {
        int o = base + incl - v;
        offv[n] = o;
        csr[o] = n;   // self loop at slot 0
        fill[n] = 1;
    }
}

__global__ void scatter_kernel(const int* __restrict__ src, const int* __restrict__ dst, int E,
                               const int* __restrict__ offv, int* __restrict__ fill,
                               int* __restrict__ csr)
{
    for (int e = blockIdx.x * blockDim.x + threadIdx.x; e < E; e += gridDim.x * blockDim.x) {
        int d = dst[e];
        int pos = offv[d] + atomicAdd(&fill[d], 1);
        csr[pos] = src[e];
    }
}

// ---------------- GAT layer 1: fused single-pass (no max-shift), bias + ELU ----------------
// A rows stride 80: [lane]=h, [64+hh]=alpha_src[head]. Unnormalized p accumulated, 1 div/node.
__global__ __launch_bounds__(256) void gat1_kernel(
    const float* __restrict__ A, const float* __restrict__ adn,
    const float* __restrict__ b1, const int* __restrict__ offv, const int* __restrict__ cnt,
    const int* __restrict__ csr, float* __restrict__ h2, int N)
{
    int n = blockIdx.x * 4 + (threadIdx.x >> 6);
    if (n >= N) return;
    int lane = threadIdx.x & 63;
    int base = offv[n];
    int deg = cnt[n] + 1;
    int hh = lane >> 3;
    float ad = adn[n * 8 + hh];
    float acc = 0.f, psum = 0.f;

    if (deg <= 64) {
        int sreg = csr[base + (lane < deg ? lane : 0)];
        int k = 0;
        for (; k + 4 <= deg; k += 4) {
            const float* r0 = A + (size_t)readlane_i(sreg, k)     * 80;
            const float* r1 = A + (size_t)readlane_i(sreg, k + 1) * 80;
            const float* r2 = A + (size_t)readlane_i(sreg, k + 2) * 80;
            const float* r3 = A + (size_t)readlane_i(sreg, k + 3) * 80;
            float h0 = r0[lane], a0 = r0[64 + hh];
            float h1v = r1[lane], a1 = r1[64 + hh];
            float h2v = r2[lane], a2 = r2[64 + hh];
            float h3 = r3[lane], a3 = r3[64 + hh];
            float p0 = __expf(lrelu(a0 + ad));
            float p1 = __expf(lrelu(a1 + ad));
            float p2 = __expf(lrelu(a2 + ad));
            float p3 = __expf(lrelu(a3 + ad));
            acc += p0 * h0 + p1 * h1v + p2 * h2v + p3 * h3;
            psum += (p0 + p1) + (p2 + p3);
        }
        for (; k < deg; ++k) {
            const float* r = A + (size_t)readlane_i(sreg, k) * 80;
            float p = __expf(lrelu(r[64 + hh] + ad));
            acc += p * r[lane];
            psum += p;
        }
    } else {
        for (int k = 0; k < deg; ++k) {
            int s = __builtin_amdgcn_readfirstlane(csr[base + k]);
            const float* r = A + (size_t)s * 80;
            float p = __expf(lrelu(r[64 + hh] + ad));
            acc += p * r[lane];
            psum += p;
        }
    }
    float v = acc / psum + b1[lane];
    h2[(size_t)n * 64 + lane] = v > 0.f ? v : __expf(v) - 1.f;  // ELU
}

// ---------------- GAT layer 2: fused single-pass, 1 head, bias ----------------
// Z rows stride 80: [lane]=z, [64]=alpha_src. Output dense stride 64.
__global__ __launch_bounds__(256) void gat2_kernel(
    const float* __restrict__ Z, const float* __restrict__ adn,
    const float* __restrict__ b2, const int* __restrict__ offv, const int* __restrict__ cnt,
    const int* __restrict__ csr, float* __restrict__ out, int N)
{
    int n = blockIdx.x * 4 + (threadIdx.x >> 6);
    if (n >= N) return;
    int lane = threadIdx.x & 63;
    int base = offv[n];
    int deg = cnt[n] + 1;
    float ad = adn[n];
    float acc = 0.f, psum = 0.f;

    if (deg <= 64) {
        int sreg = csr[base + (lane < deg ? lane : 0)];
        int k = 0;
        for (; k + 4 <= deg; k += 4) {
            const float* r0 = Z + (size_t)readlane_i(sreg, k)     * 80;
            const float* r1 = Z + (size_t)readlane_i(sreg, k + 1) * 80;
            const float* r2 = Z + (size_t)readlane_i(sreg, k + 2) * 80;
            const float* r3 = Z + (size_t)readlane_i(sreg, k + 3) * 80;
            float z0 = r0[lane], a0 = r0[64];
            float z1 = r1[lane], a1 = r1[64];
            float z2 = r2[lane], a2 = r2[64];
            float z3 = r3[lane], a3 = r3[64];
            float p0 = __expf(lrelu(a0 + ad));
            float p1 = __expf(lrelu(a1 + ad));
            float p2 = __expf(lrelu(a2 + ad));
            float p3 = __expf(lrelu(a3 + ad));
            acc += p0 * z0 + p1 * z1 + p2 * z2 + p3 * z3;
            psum += (p0 + p1) + (p2 + p3);
        }
        for (; k < deg; ++k) {
            const float* r = Z + (size_t)readlane_i(sreg, k) * 80;
            float p = __expf(lrelu(r[64] + ad));
            acc += p * r[lane];
            psum += p;
        }
    } else {
        for (int k = 0; k < deg; ++k) {
            int s = __builtin_amdgcn_readfirstlane(csr[base + k]);
            const float* r = Z + (size_t)s * 80;
            float p = __expf(lrelu(r[64] + ad));
            acc += p * r[lane];
            psum += p;
        }
    }
    out[(size_t)n * 64 + lane] = acc / psum + b2[lane];
}

// ---------------- decode: sigmoid(dot(z2[q0], z2[q1])) ----------------
__global__ __launch_bounds__(256) void decode_kernel(
    const float* __restrict__ z2, const int* __restrict__ q, int Q, float* __restrict__ out)
{
    int i = blockIdx.x * 4 + (threadIdx.x >> 6);
    if (i >= Q) return;
    int lane = threadIdx.x & 63;
    int a = q[i], b = q[Q + i];
    float v = z2[(size_t)a * 64 + lane] * z2[(size_t)b * 64 + lane];
#pragma unroll
    for (int d = 1; d < 64; d <<= 1) v += __shfl_xor(v, d);
    if (lane == 0) out[i] = 1.f / (1.f + __expf(-v));
}

extern "C" void kernel_launch(void* const* d_in, const int* in_sizes, int n_in,
                              void* d_out, int out_size, void* d_ws, size_t ws_size,
                              hipStream_t stream)
{
    const float* x   = (const float*)d_in[0];
    const int*   ei  = (const int*)d_in[1];
    const int*   qe  = (const int*)d_in[2];
    const float* W1  = (const float*)d_in[3];
    const float* as1 = (const float*)d_in[4];
    const float* ad1 = (const float*)d_in[5];
    const float* b1  = (const float*)d_in[6];
    const float* W2  = (const float*)d_in[7];
    const float* as2 = (const float*)d_in[8];
    const float* ad2 = (const float*)d_in[9];
    const float* b2  = (const float*)d_in[10];

    const int N = in_sizes[0] / 128;
    const int E = in_sizes[1] / 2;
    const int Q = in_sizes[2] / 2;

    float* out = (float*)d_out;

    char* ws = (char*)d_ws;
    size_t o = 0;
    auto alloc = [&](size_t bytes) -> void* {
        void* p = ws + o;
        o += (bytes + 255) & ~(size_t)255;
        return p;
    };
    float* bufA  = (float*)alloc((size_t)N * 80 * 4);  // h1+as1 rows, later z+as2 rows
    float* bufB  = (float*)alloc((size_t)N * 64 * 4);  // h2 dense, later final embeddings
    float* adn1  = (float*)alloc((size_t)N * 8 * 4);
    float* adn2  = (float*)alloc((size_t)N * 4);
    int*   cnt   = (int*)alloc((size_t)N * 4);
    int*   offv  = (int*)alloc((size_t)N * 4);
    int*   fill  = (int*)alloc((size_t)N * 4);
    int*   cursor= (int*)alloc(256);
    int*   csr   = (int*)alloc((size_t)(E + N) * 4);

    const int* esrc = ei;
    const int* edst = ei + E;

    hipMemsetAsync(cnt, 0, (size_t)N * 4, stream);
    hipMemsetAsync(cursor, 0, 4, stream);

    int nodeBlocks4 = (N + 3) / 4;
    int tileBlocks  = (N + 63) / 64;
    int edgeBlocks  = (E + 255) / 256;
    int nodeBlocks  = (N + 255) / 256;

    gemm1_kernel<<<tileBlocks, 256, 0, stream>>>(x, W1, as1, ad1, bufA, adn1, N);
    count_kernel<<<edgeBlocks, 256, 0, stream>>>(edst, E, cnt);
    offsets_kernel<<<nodeBlocks, 256, 0, stream>>>(cnt, N, offv, fill, csr, cursor);
    scatter_kernel<<<edgeBlocks, 256, 0, stream>>>(esrc, edst, E, offv, fill, csr);
    gat1_kernel<<<nodeBlocks4, 256, 0, stream>>>(bufA, adn1, b1, offv, cnt, csr, bufB, N);
    gemm2_kernel<<<tileBlocks, 256, 0, stream>>>(bufB, W2, as2, ad2, bufA, adn2, N);
    gat2_kernel<<<nodeBlocks4, 256, 0, stream>>>(bufA, adn2, b2, offv, cnt, csr, bufB, N);
    decode_kernel<<<(Q + 3) / 4, 256, 0, stream>>>(bufB, qe, Q, out);
}